// Round 4
// baseline (2405.779 us; speedup 1.0000x reference)
//
#include <hip/hip_runtime.h>

#define IMH 64
#define IMW 64
#define HWSZ 4096
#define BATCH 16
#define TSTEPS 16

typedef _Float16 half8 __attribute__((ext_vector_type(8)));
typedef float floatx4 __attribute__((ext_vector_type(4)));

__device__ __forceinline__ float sigmoidf_(float x) { return 1.f / (1.f + __expf(-x)); }
__device__ __forceinline__ float tanhf_(float x) { return 1.f - 2.f / (1.f + __expf(2.f * x)); }

__device__ __forceinline__ void gld_lds16(const void* g, void* l) {
    __builtin_amdgcn_global_load_lds(
        (const __attribute__((address_space(1))) unsigned int*)g,
        (__attribute__((address_space(3))) unsigned int*)l, 16, 0, 0);
}

// repack fp32 w [256][CIN][3][3] -> f16 wr [chunk][tap][g][hg][m16][k32]
// out = g*64 + hg*16 + m ; ci = chunk*32 + k (zero past cin)
__global__ void repack_f16_kernel(const float* __restrict__ w, _Float16* __restrict__ wr,
                                  int nchunk, int cin) {
    int total = nchunk * 9 * 8192;
    for (int idx = blockIdx.x * blockDim.x + threadIdx.x; idx < total;
         idx += gridDim.x * blockDim.x) {
        int k = idx & 31;
        int t = idx >> 5;
        int m = t & 15; t >>= 4;
        int hg = t & 3; t >>= 2;
        int g = t & 3; t >>= 2;
        int tap = t % 9;
        int chunk = t / 9;
        int out = g * 64 + hg * 16 + m;
        int ci = chunk * 32 + k;
        float v = (ci < cin) ? w[(out * cin + ci) * 9 + tap] : 0.f;
        wr[idx] = (_Float16)v;
    }
}

// Fused conv3x3(concat(xin,hprev)) -> 4 gates -> LSTM update. f16 MFMA implicit GEMM.
// Block: 512 thr (8 waves), 4 image rows x 64 cols. Wave (hg=wv&3, p=wv>>2):
// M=64 (4 gates x 16 hids of group hg), N=128 px (rows 2p,2p+1; ni 0..7).
// All LDS accesses are dense contiguous 1KB wave reads/writes (conflict-free).
// Weights double-buffered in LDS via global_load_lds, prefetched one tap ahead.
template<int NCHUNK, int CIN, int XIN>
__global__ __launch_bounds__(512, 2) void lstm_mfma_kernel(
    const float* __restrict__ xin, int xbs,      // first XIN channels, batch stride
    const float* __restrict__ hprev,             // [B][64][H][W] (channels XIN..)
    float* __restrict__ hnew,                    // [B][64][H][W]
    float* __restrict__ cstate,                  // in-place [B][64][H][W]
    const _Float16* __restrict__ wr,             // [NCHUNK][9][8192]
    const float* __restrict__ bias)              // [256]
{
    __shared__ __align__(16) _Float16 wlds[2][8192];       // 2 x 16 KB
    __shared__ __align__(16) _Float16 actlds[6 * 66 * 32]; // 24.75 KB

    const int tid = threadIdx.x;
    const int lane = tid & 63;
    const int n = lane & 15, q = lane >> 4;
    const int wv = tid >> 6;
    const int hg = wv & 3;
    const int p = wv >> 2;
    const int rb = blockIdx.x;                   // 4-row block 0..15
    const int b = blockIdx.y;
    const int by0 = rb * 4 - 1;                  // halo row origin

    floatx4 acc[4][8];
    #pragma unroll
    for (int g = 0; g < 4; ++g)
        #pragma unroll
        for (int i = 0; i < 8; ++i) acc[g][i] = (floatx4){0.f, 0.f, 0.f, 0.f};

    auto issue_w = [&](int gt) {
        const _Float16* src = wr + (size_t)gt * 8192;
        _Float16* dst = wlds[gt & 1];
        #pragma unroll
        for (int i = 0; i < 2; ++i)
            gld_lds16(src + (size_t)(tid + i * 512) * 8, dst + (tid + i * 512) * 8);
    };

    issue_w(0);

    for (int chunk = 0; chunk < NCHUNK; ++chunk) {
        __syncthreads();   // act buffer reusable (prev chunk's MFMAs done)
        // stage 6 halo rows x 66 cols x 32 ch (f16, ch-fastest, dense writes)
        for (int e = tid; e < 6 * 66 * 4; e += 512) {
            int g = e & 3;
            int pix = e >> 2;
            int cs = pix % 66;
            int r = pix / 66;
            int gy = by0 + r, gx = cs - 1;
            bool inb = (gy >= 0) && (gy < IMH) && (gx >= 0) && (gx < IMW);
            int ch0 = chunk * 32 + g * 8;
            half8 hv;
            #pragma unroll
            for (int j = 0; j < 8; ++j) {
                int vc = ch0 + j;
                float xv = 0.f;
                if (inb && vc < CIN)
                    xv = (vc < XIN)
                       ? xin[(size_t)b * xbs + (size_t)vc * HWSZ + gy * IMW + gx]
                       : hprev[(size_t)(b * 64 + (vc - XIN)) * HWSZ + gy * IMW + gx];
                hv[j] = (_Float16)xv;
            }
            *(half8*)&actlds[(r * 66 + cs) * 32 + g * 8] = hv;
        }

        #pragma unroll
        for (int tap = 0; tap < 9; ++tap) {
            const int gt = chunk * 9 + tap;
            __syncthreads();   // vmcnt drain -> wlds[gt&1] ready; act visible
            if (gt + 1 < NCHUNK * 9) issue_w(gt + 1);
            const _Float16* wb = wlds[gt & 1];
            const int dy = tap / 3, dx = tap % 3;
            half8 bfr[8];
            #pragma unroll
            for (int ni = 0; ni < 8; ++ni) {
                int row = p * 2 + (ni >> 2) + dy;
                int col = 16 * (ni & 3) + n + dx;
                bfr[ni] = *(const half8*)&actlds[(row * 66 + col) * 32 + q * 8];
            }
            #pragma unroll
            for (int g = 0; g < 4; ++g) {
                half8 afr = *(const half8*)&wb[((g * 4 + hg) * 16 + n) * 32 + q * 8];
                #pragma unroll
                for (int ni = 0; ni < 8; ++ni)
                    acc[g][ni] = __builtin_amdgcn_mfma_f32_16x16x32_f16(
                        afr, bfr[ni], acc[g][ni], 0, 0, 0);
            }
        }
    }

    // LSTM pointwise update in-register:
    // lane gates for h = hg*16 + q*4 + r ; px: row rb*4 + 2p + (ni>>2), col 16*(ni&3)+n
    const int hb = hg * 16 + q * 4;
    floatx4 bi = *(const floatx4*)&bias[hb];
    floatx4 bf = *(const floatx4*)&bias[64 + hb];
    floatx4 bo = *(const floatx4*)&bias[128 + hb];
    floatx4 bg = *(const floatx4*)&bias[192 + hb];
    #pragma unroll
    for (int ni = 0; ni < 8; ++ni) {
        int y = rb * 4 + p * 2 + (ni >> 2);
        int col = 16 * (ni & 3) + n;
        #pragma unroll
        for (int r = 0; r < 4; ++r) {
            size_t idx = (size_t)(b * 64 + hb + r) * HWSZ + y * IMW + col;
            float zi = acc[0][ni][r] + bi[r];
            float zf = acc[1][ni][r] + bf[r];
            float zo = acc[2][ni][r] + bo[r];
            float zg = acc[3][ni][r] + bg[r];
            float cv = cstate[idx];
            float cn = fmaf(sigmoidf_(zf), cv, sigmoidf_(zi) * tanhf_(zg));
            cstate[idx] = cn;
            hnew[idx] = sigmoidf_(zo) * tanhf_(cn);
        }
    }
}

__global__ void head_kernel(const float* __restrict__ h1,
                            const float* __restrict__ wh,
                            const float* __restrict__ bh,
                            float* __restrict__ out) {
    int nn = blockIdx.x * blockDim.x + threadIdx.x;  // 0..65535
    int b = nn >> 12;
    int pp = nn & 4095;
    float s = bh[0];
    #pragma unroll 8
    for (int h = 0; h < 64; ++h)
        s = fmaf(h1[(size_t)(b * 64 + h) * HWSZ + pp], wh[h], s);
    out[nn] = fmaxf(s, 0.f);
}

extern "C" void kernel_launch(void* const* d_in, const int* in_sizes, int n_in,
                              void* d_out, int out_size, void* d_ws, size_t ws_size,
                              hipStream_t stream) {
    const float* x  = (const float*)d_in[0];
    const float* w0 = (const float*)d_in[1];
    const float* b0 = (const float*)d_in[2];
    const float* w1 = (const float*)d_in[3];
    const float* b1 = (const float*)d_in[4];
    const float* wh = (const float*)d_in[5];
    const float* bh = (const float*)d_in[6];
    float* out = (float*)d_out;

    const size_t BUF = (size_t)BATCH * 64 * HWSZ;    // 4,194,304 floats (16 MB)
    float* ws  = (float*)d_ws;
    float* h0a = ws;                 // zero-init
    float* c0  = ws + BUF;           // zero-init
    float* h1a = ws + 2 * BUF;       // zero-init
    float* c1  = ws + 3 * BUF;       // zero-init
    float* h0b = ws + 4 * BUF;
    float* h1b = ws + 5 * BUF;
    _Float16* wr0 = (_Float16*)(ws + 6 * BUF);       // 3*9*8192 = 221,184 halves
    _Float16* wr1 = wr0 + (size_t)3 * 9 * 8192;      // 4*9*8192 = 294,912 halves

    hipMemsetAsync(d_ws, 0, 4 * BUF * sizeof(float), stream);
    repack_f16_kernel<<<864, 256, 0, stream>>>(w0, wr0, 3, 65);
    repack_f16_kernel<<<1152, 256, 0, stream>>>(w1, wr1, 4, 128);

    float* h0buf[2] = {h0a, h0b};
    float* h1buf[2] = {h1a, h1b};
    dim3 grid(16, BATCH), block(512);                // 256 blocks = 1/CU
    for (int t = 0; t < TSTEPS; ++t) {
        int cur = t & 1, nxt = cur ^ 1;
        lstm_mfma_kernel<3, 65, 1><<<grid, block, 0, stream>>>(
            x + (size_t)t * HWSZ, TSTEPS * HWSZ,
            h0buf[cur], h0buf[nxt], c0, wr0, b0);
        lstm_mfma_kernel<4, 128, 64><<<grid, block, 0, stream>>>(
            h0buf[nxt], 64 * HWSZ,
            h1buf[cur], h1buf[nxt], c1, wr1, b1);
    }
    // t=15 wrote h1buf[0]
    head_kernel<<<256, 256, 0, stream>>>(h1buf[0], wh, bh, out);
}

// Round 5
// 1908.439 us; speedup vs baseline: 1.2606x; 1.2606x over previous
//
#include <hip/hip_runtime.h>

#define IMH 64
#define IMW 64
#define HWSZ 4096
#define BATCH 16
#define TSTEPS 16
#define PADW 66

typedef _Float16 half8 __attribute__((ext_vector_type(8)));
typedef _Float16 half4 __attribute__((ext_vector_type(4)));
typedef float floatx4 __attribute__((ext_vector_type(4)));

__device__ __forceinline__ float sigmoidf_(float x) { return 1.f / (1.f + __expf(-x)); }
__device__ __forceinline__ float tanhf_(float x) { return 1.f - 2.f / (1.f + __expf(2.f * x)); }

__device__ __forceinline__ void gld_lds16(const void* g, void* l) {
    __builtin_amdgcn_global_load_lds(
        (const __attribute__((address_space(1))) unsigned int*)g,
        (__attribute__((address_space(3))) unsigned int*)l, 16, 0, 0);
}

// Weight repack: wr[gt][1280 slots][8 halves]; slot l: m = l/5, sl = l%5 (sl==4: pad=0).
// LDS m -> out: bidx=m>>4, g=bidx>>2, hg=bidx&3, out = g*64+hg*16+(m&15).
// k within chunk = sl*8+j ; xmode: kg<64 -> ci=kg+1 (h), kg==64 -> ci=0 (x), else 0.
__global__ void repack_w(const float* __restrict__ w, _Float16* __restrict__ wr,
                         int ngt, int cin, int xmode) {
    int total = ngt * 10240;
    for (int idx = blockIdx.x * blockDim.x + threadIdx.x; idx < total;
         idx += gridDim.x * blockDim.x) {
        int j = idx & 7;
        int l = (idx >> 3) % 1280;
        int gt = idx / 10240;
        int m = l / 5, sl = l - m * 5;
        int chunk = gt / 9, tap = gt - chunk * 9;
        int bidx = m >> 4, i = m & 15;
        int g = bidx >> 2, hg = bidx & 3;
        int out = g * 64 + hg * 16 + i;
        float v = 0.f;
        if (sl < 4) {
            int kg = chunk * 32 + sl * 8 + j;
            int ci = xmode ? (kg < 64 ? kg + 1 : (kg == 64 ? 0 : -1))
                           : (kg < cin ? kg : -1);
            if (ci >= 0) v = w[(out * cin + ci) * 9 + tap];
        }
        wr[idx] = (_Float16)v;
    }
}

// Fused conv3x3 -> 4 gates -> LSTM update. f16 MFMA implicit GEMM.
// Block: 256 thr (4 waves = 4 hid-groups), 2 image rows x 64 cols (N=128).
// h state lives as padded f16 pixel-major [B][66][66][64] -> act staging is pure
// global_load_lds DMA. LDS pixel stride 80B (4 data slots + 1 pad) -> bank-quad
// = (5n+q) mod 8 -> max 2-way conflict (free). Weights dbuf per tap, same stride.
template<int NCHUNK, int XCHUNK>
__global__ __launch_bounds__(256, 2) void lstm_mfma_kernel(
    const _Float16* __restrict__ srcA,    // chunks 0-1 (padded pixel-major)
    const _Float16* __restrict__ srcB,    // chunks 2-3
    const float* __restrict__ xsrc,       // layer0 x_t (batch stride TSTEPS*HWSZ)
    _Float16* __restrict__ hpad,          // out h [B][66][66][64]
    float* __restrict__ cpix,             // in-place c [B][4096][64]
    const _Float16* __restrict__ wr,      // [NGT][10240]
    const float* __restrict__ bias)       // [256]
{
    __shared__ __align__(16) _Float16 wlds[2][10240];  // 2 x 20 KB
    __shared__ __align__(16) _Float16 act[10560];      // 1320 slots x 16B = 20.6 KB

    const int tid = threadIdx.x;
    const int lane = tid & 63;
    const int n = lane & 15, q = lane >> 4;
    const int hg = tid >> 6;                 // wave = hid group 0..3
    const int rb = blockIdx.x;               // row pair 0..31
    const int b = blockIdx.y;

    floatx4 acc[4][8];
    #pragma unroll
    for (int g = 0; g < 4; ++g)
        #pragma unroll
        for (int i = 0; i < 8; ++i) acc[g][i] = (floatx4){0.f, 0.f, 0.f, 0.f};

    auto issue_w = [&](int gt) {
        const _Float16* src = wr + (size_t)gt * 10240;
        _Float16* dst = wlds[gt & 1];
        #pragma unroll
        for (int i2 = 0; i2 < 5; ++i2)
            gld_lds16(src + (size_t)(tid + i2 * 256) * 8, dst + (tid + i2 * 256) * 8);
    };
    issue_w(0);

    constexpr int NGT = NCHUNK * 9;
    for (int chunk = 0; chunk < NCHUNK; ++chunk) {
        if (chunk) __syncthreads();          // all reads of prev chunk done
        if (chunk == XCHUNK) {
            // layer0 x chunk: k=0 is x, rest zeros (written by VALU, tiny)
            for (int t = tid; t < 1320; t += 256) {
                int r = t / 330, u = t - r * 330;
                int cs = u / 5, sl = u - cs * 5;
                half8 hv;
                #pragma unroll
                for (int j = 0; j < 8; ++j) hv[j] = (_Float16)0.f;
                if (sl == 0) {
                    int gy = rb * 2 - 1 + r, gx = cs - 1;
                    float v = 0.f;
                    if (gy >= 0 && gy < IMH && gx >= 0 && gx < IMW)
                        v = xsrc[(size_t)b * (TSTEPS * HWSZ) + gy * IMW + gx];
                    hv[0] = (_Float16)v;
                }
                *(half8*)&act[t * 8] = hv;
            }
        } else {
            const _Float16* buf = (chunk < 2) ? srcA : srcB;
            const int halfsel = chunk & 1;
            for (int t = tid; t < 1320; t += 256) {
                int r = t / 330, u = t - r * 330;
                int cs = u / 5, sl = u - cs * 5;
                int sle = (sl == 4) ? 3 : sl;          // pad slot: safe dup read
                const _Float16* g = buf
                    + ((size_t)(b * PADW + rb * 2 + r) * PADW + cs) * 64
                    + halfsel * 32 + sle * 8;
                gld_lds16(g, &act[t * 8]);
            }
        }
        #pragma unroll
        for (int tap = 0; tap < 9; ++tap) {
            const int gt = chunk * 9 + tap;
            __syncthreads();                 // vmcnt drain: act + wlds[gt&1] ready
            if (gt + 1 < NGT) issue_w(gt + 1);
            const _Float16* wb = wlds[gt & 1];
            const int dy = tap / 3, dx = tap - dy * 3;
            half8 bfr[8];
            #pragma unroll
            for (int ni = 0; ni < 8; ++ni) {
                int row = (ni >> 2) + dy;                // 0..3
                int col = 16 * (ni & 3) + n + dx;        // 0..65
                bfr[ni] = *(const half8*)&act[(row * 330 + col * 5 + q) * 8];
            }
            #pragma unroll
            for (int g = 0; g < 4; ++g) {
                half8 afr = *(const half8*)&wb[(((g * 4 + hg) * 16 + n) * 5 + q) * 8];
                #pragma unroll
                for (int ni = 0; ni < 8; ++ni)
                    acc[g][ni] = __builtin_amdgcn_mfma_f32_16x16x32_f16(
                        afr, bfr[ni], acc[g][ni], 0, 0, 0);
            }
        }
    }

    // Epilogue: lane holds gates for h = hg*16+q*4+r, pixel row rb*2+(ni>>2), col 16*(ni&3)+n
    const int hb = hg * 16 + q * 4;
    floatx4 bi = *(const floatx4*)&bias[hb];
    floatx4 bf = *(const floatx4*)&bias[64 + hb];
    floatx4 bo = *(const floatx4*)&bias[128 + hb];
    floatx4 bg = *(const floatx4*)&bias[192 + hb];
    #pragma unroll
    for (int ni = 0; ni < 8; ++ni) {
        int y = rb * 2 + (ni >> 2);
        int col = 16 * (ni & 3) + n;
        size_t cidx = ((size_t)b * HWSZ + y * IMW + col) * 64 + hb;
        floatx4 cold = *(const floatx4*)&cpix[cidx];
        floatx4 cnew;
        half4 hv;
        #pragma unroll
        for (int r = 0; r < 4; ++r) {
            float zi = acc[0][ni][r] + bi[r];
            float zf = acc[1][ni][r] + bf[r];
            float zo = acc[2][ni][r] + bo[r];
            float zg = acc[3][ni][r] + bg[r];
            float cn = fmaf(sigmoidf_(zf), cold[r], sigmoidf_(zi) * tanhf_(zg));
            cnew[r] = cn;
            hv[r] = (_Float16)(sigmoidf_(zo) * tanhf_(cn));
        }
        *(floatx4*)&cpix[cidx] = cnew;
        *(half4*)&hpad[((size_t)(b * PADW + y + 1) * PADW + col + 1) * 64 + hb] = hv;
    }
}

__global__ void head_kernel(const _Float16* __restrict__ h1pad,
                            const float* __restrict__ wh,
                            const float* __restrict__ bh,
                            float* __restrict__ out) {
    int nn = blockIdx.x * blockDim.x + threadIdx.x;  // 0..65535
    int b = nn >> 12, pp = nn & 4095;
    int y = pp >> 6, xc = pp & 63;
    const _Float16* base = h1pad + ((size_t)(b * PADW + y + 1) * PADW + xc + 1) * 64;
    float s = bh[0];
    #pragma unroll
    for (int h0 = 0; h0 < 64; h0 += 8) {
        half8 hv = *(const half8*)&base[h0];
        #pragma unroll
        for (int j = 0; j < 8; ++j) s = fmaf((float)hv[j], wh[h0 + j], s);
    }
    out[nn] = fmaxf(s, 0.f);
}

extern "C" void kernel_launch(void* const* d_in, const int* in_sizes, int n_in,
                              void* d_out, int out_size, void* d_ws, size_t ws_size,
                              hipStream_t stream) {
    const float* x  = (const float*)d_in[0];
    const float* w0 = (const float*)d_in[1];
    const float* b0 = (const float*)d_in[2];
    const float* w1 = (const float*)d_in[3];
    const float* b1 = (const float*)d_in[4];
    const float* wh = (const float*)d_in[5];
    const float* bh = (const float*)d_in[6];
    float* out = (float*)d_out;

    const size_t HPAD = (size_t)BATCH * PADW * PADW * 64;  // 4,460,544 halves
    const size_t CBUF = (size_t)BATCH * HWSZ * 64;         // 4,194,304 floats
    _Float16* hp  = (_Float16*)d_ws;
    _Float16* h0a = hp;
    _Float16* h0b = hp + HPAD;
    _Float16* h1a = hp + 2 * HPAD;
    _Float16* h1b = hp + 3 * HPAD;
    float* cbase = (float*)(hp + 4 * HPAD);
    float* c0 = cbase;
    float* c1 = cbase + CBUF;
    _Float16* wr0 = (_Float16*)(cbase + 2 * CBUF);   // 27*10240 halves
    _Float16* wr1 = wr0 + (size_t)27 * 10240;        // 36*10240 halves

    // zero h buffers (borders must stay 0) and c buffers
    hipMemsetAsync(d_ws, 0, 4 * HPAD * sizeof(_Float16) + 2 * CBUF * sizeof(float), stream);
    repack_w<<<1080, 256, 0, stream>>>(w0, wr0, 27, 65, 1);
    repack_w<<<1440, 256, 0, stream>>>(w1, wr1, 36, 128, 0);

    _Float16* h0buf[2] = {h0a, h0b};
    _Float16* h1buf[2] = {h1a, h1b};
    dim3 grid(32, BATCH), block(256);                // 512 blocks = 2/CU
    for (int t = 0; t < TSTEPS; ++t) {
        int cur = t & 1, nxt = cur ^ 1;
        // layer0: chunks = [h0 ch0-31][h0 ch32-63][x + zeros]
        lstm_mfma_kernel<3, 2><<<grid, block, 0, stream>>>(
            h0buf[cur], (const _Float16*)nullptr, x + (size_t)t * HWSZ,
            h0buf[nxt], c0, wr0, b0);
        // layer1: chunks = [h0new 0-31][h0new 32-63][h1 0-31][h1 32-63]
        lstm_mfma_kernel<4, -1><<<grid, block, 0, stream>>>(
            h0buf[nxt], h1buf[cur], (const float*)nullptr,
            h1buf[nxt], c1, wr1, b1);
    }
    // t=15 wrote h1buf[0]
    head_kernel<<<256, 256, 0, stream>>>(h1buf[0], wh, bh, out);
}